// Round 6
// baseline (327.803 us; speedup 1.0000x reference)
//
#include <hip/hip_runtime.h>
#include <math.h>

#define BS 256
#define V 10475
#define NJ 55
#define R3 31425      // V*3
#define NP 486        // 54*9
#define LB 60         // effective betas (10 shape + 50 expression)
#define KP 576        // padded K (486 pose + 60 shape)
#define VK 10496      // V padded to mult of 128 (82*128)
#define JOFF 8044800  // BS*R3 — joints output offset
#define PR 65         // k_gemm LDS pitch in dwords (odd → bank spread)

typedef __attribute__((ext_vector_type(8))) short short8;
typedef __attribute__((ext_vector_type(4))) float float4_;
typedef __attribute__((ext_vector_type(4))) unsigned int uint4_;

__device__ const int PARENTS_d[NJ] = {
  -1, 0, 0, 0, 1, 2, 3, 4, 5, 6, 7, 8, 9, 9, 9, 12, 13, 14, 16, 17, 18, 19,
  15, 15, 15, 20, 25, 26, 20, 28, 29, 20, 31, 32, 20, 34, 35, 20, 37, 38,
  21, 40, 41, 21, 43, 44, 21, 46, 47, 21, 49, 50, 21, 52, 53
};

__device__ __forceinline__ unsigned short f2b(float f) {
  unsigned int u = __float_as_uint(f);
  unsigned int r = (u + 0x7FFFu + ((u >> 16) & 1u)) >> 16;
  return (unsigned short)r;
}

// ---------------- K1: rodrigues + Ftr bf16 [b][576] + betas_T fp32 --------
__global__ __launch_bounds__(256) void k_pose(
    const float* __restrict__ pose, const float* __restrict__ shp,
    const float* __restrict__ expr, const float* __restrict__ go,
    float* __restrict__ rot_ws, unsigned short* __restrict__ Ftr,
    float* __restrict__ betas_T) {
  int b = threadIdx.x;
  int j = blockIdx.x;
  if (j == NJ) {  // betas block: Ftr rows 486..575 + betas_T
    #pragma unroll
    for (int l = 0; l < 10; ++l) {
      float v = shp[b * 10 + l];
      betas_T[l * BS + b] = v;
      Ftr[(size_t)b * KP + NP + l] = f2b(v);
    }
    #pragma unroll
    for (int l = 0; l < 50; ++l) {
      float v = expr[b * 50 + l];
      betas_T[(10 + l) * BS + b] = v;
      Ftr[(size_t)b * KP + NP + 10 + l] = f2b(v);
    }
    #pragma unroll
    for (int l = NP + LB; l < KP; ++l) Ftr[(size_t)b * KP + l] = 0;
    return;
  }
  float rx, ry, rz;
  if (j == 0) { rx = go[0]; ry = go[1]; rz = go[2]; }
  else if (j == 23 || j == 24) { rx = 0.f; ry = 0.f; rz = 0.f; }
  else {
    int src = (j <= 21) ? j : (j == 22 ? 52 : j - 3);
    const float* p = pose + ((size_t)b * 53 + src) * 3;
    rx = p[0]; ry = p[1]; rz = p[2];
  }
  float sx = rx + 1e-8f, sy = ry + 1e-8f, sz = rz + 1e-8f;
  float ang = sqrtf(sx * sx + sy * sy + sz * sz);
  float inv = 1.f / ang;
  float x = rx * inv, y = ry * inv, z = rz * inv;
  float s = sinf(ang), c = cosf(ang), C = 1.f - c;
  float R[9];
  R[0] = 1.f - C * (y * y + z * z);
  R[1] = -s * z + C * x * y;
  R[2] =  s * y + C * x * z;
  R[3] =  s * z + C * x * y;
  R[4] = 1.f - C * (x * x + z * z);
  R[5] = -s * x + C * y * z;
  R[6] = -s * y + C * x * z;
  R[7] =  s * x + C * y * z;
  R[8] = 1.f - C * (x * x + y * y);
  float* rw = rot_ws + ((size_t)b * NJ + j) * 9;
  #pragma unroll
  for (int e = 0; e < 9; ++e) rw[e] = R[e];
  if (j >= 1) {
    int pb = (j - 1) * 9;
    #pragma unroll
    for (int e = 0; e < 9; ++e)
      Ftr[(size_t)b * KP + pb + e] =
          f2b(R[e] - ((e == 0 || e == 4 || e == 8) ? 1.f : 0.f));
  }
}

// ---------------- K1b: Jregb[64][VK] bf16 = pad(Jreg) ---------------------
__global__ __launch_bounds__(256) void k_jregb(
    const float* __restrict__ Jreg, unsigned short* __restrict__ Jregb) {
  size_t idx = (size_t)blockIdx.x * 256 + threadIdx.x;  // 64*VK total
  int j = (int)(idx / VK);
  int v = (int)(idx - (size_t)j * VK);
  float val = (j < NJ && v < V) ? Jreg[(size_t)j * V + v] : 0.f;
  Jregb[idx] = f2b(val);
}

// ---------------- K1c: XbT[192][VK] bf16 — sd live cols + vt, v-contig ----
__global__ __launch_bounds__(256) void k_trX(
    const float* __restrict__ sd, const float* __restrict__ vt,
    unsigned short* __restrict__ XbT) {
  __shared__ float tile[192][65];
  int t = threadIdx.x;
  int v0 = blockIdx.x * 64;
  #pragma unroll 1
  for (int c = 0; c < 3; ++c) {
    for (int idx = t; idx < 3840; idx += 256) {
      int v_l = idx / 60, col = idx - v_l * 60;
      int v = v0 + v_l;
      int cidx = (col < 10) ? col : 290 + col;
      float val = (v < V) ? sd[((size_t)v * 3 + c) * 350 + cidx] : 0.f;
      tile[c * 64 + col][v_l] = val;
    }
  }
  for (int idx = t; idx < 768; idx += 256) {
    int v_l = idx & 63, rr = idx >> 6;
    int c = rr >> 2, l = 60 + (rr & 3);
    int v = v0 + v_l;
    float val = (l == 60 && v < V) ? vt[(size_t)v * 3 + c] : 0.f;
    tile[c * 64 + l][v_l] = val;
  }
  __syncthreads();
  for (int idx = t; idx < 192 * 64; idx += 256) {
    int cl = idx >> 6, v_l = idx & 63;
    XbT[(size_t)cl * VK + v0 + v_l] = f2b(tile[cl][v_l]);
  }
}

// ---------------- K2: JS via MFMA — M=64(j) N=192(3c*64) K=VK -------------
// 164 blocks x 64 K each
__global__ __launch_bounds__(256) void k_jsm(
    const unsigned short* __restrict__ Jregb,
    const unsigned short* __restrict__ XbT, float* __restrict__ JS) {
  int lane = threadIdx.x & 63;
  int wv = threadIdx.x >> 6;
  int l15 = lane & 15, q = lane >> 4;
  int k0 = blockIdx.x * 64;
  const unsigned short* ap = Jregb + (size_t)(wv * 16 + l15) * VK + k0 + q * 8;
  float4_ acc[12];
  #pragma unroll
  for (int nt = 0; nt < 12; ++nt) acc[nt] = (float4_)0.f;
  #pragma unroll
  for (int ks = 0; ks < 2; ++ks) {
    short8 a = *(const short8*)(ap + ks * 32);
    #pragma unroll
    for (int nt = 0; nt < 12; ++nt) {
      const unsigned short* bp =
          XbT + (size_t)(nt * 16 + l15) * VK + k0 + ks * 32 + q * 8;
      short8 b = *(const short8*)bp;
      acc[nt] = __builtin_amdgcn_mfma_f32_16x16x32_bf16(a, b, acc[nt], 0, 0, 0);
    }
  }
  #pragma unroll
  for (int nt = 0; nt < 12; ++nt) {
    int cl = nt * 16 + l15;
    int c = cl >> 6, l = cl & 63;
    if (l < 61) {
      #pragma unroll
      for (int reg = 0; reg < 4; ++reg) {
        int jj = wv * 16 + q * 4 + reg;
        if (jj < NJ)
          atomicAdd(&JS[((size_t)jj * 3 + c) * 61 + l], acc[nt][reg]);
      }
    }
  }
}

// ---------------- K2c: Wb[v][64] bf16 from lbs (VK rows) ------------------
__global__ __launch_bounds__(256) void k_wb(
    const float* __restrict__ lbs, unsigned short* __restrict__ Wb) {
  int v0 = blockIdx.x * 16;
  for (int idx = threadIdx.x; idx < 1024; idx += 256) {
    int v_l = idx >> 6, k = idx & 63;
    int v = v0 + v_l;
    float val = (k < NJ && v < V) ? lbs[(size_t)v * NJ + k] : 0.f;
    if (v < VK) Wb[(size_t)v * 64 + k] = f2b(val);
  }
}

// ---------------- K3: joints + chain + arelb bf16 [b][16n][64k] -----------
__global__ __launch_bounds__(64) void k_chain(
    const float* __restrict__ JS, const float* __restrict__ betas_T,
    const float* __restrict__ rot_ws, unsigned short* __restrict__ arelb,
    float* __restrict__ out) {
  int b = blockIdx.x;
  int lane = threadIdx.x;
  __shared__ float joints_l[165];
  __shared__ float Tl[880];
  __shared__ float A[880];
  for (int idx = lane; idx < 165; idx += 64) {
    float sacc = JS[idx * 61 + 60];  // v_template column
    #pragma unroll
    for (int l = 0; l < LB; ++l) sacc += JS[idx * 61 + l] * betas_T[l * BS + b];
    joints_l[idx] = sacc;
  }
  __syncthreads();
  for (int idx = lane; idx < 880; idx += 64) {
    int j = idx >> 4, e = idx & 15, r = e >> 2, cc = e & 3;
    float val;
    if (r < 3) {
      if (cc < 3) val = rot_ws[((size_t)b * NJ + j) * 9 + r * 3 + cc];
      else {
        int par = PARENTS_d[j];
        val = joints_l[j * 3 + r] - (par >= 0 ? joints_l[par * 3 + r] : 0.f);
      }
    } else val = (cc == 3) ? 1.f : 0.f;
    Tl[idx] = val;
  }
  __syncthreads();
  if (lane < 16) A[lane] = Tl[lane];
  __syncthreads();
  for (int j = 1; j < NJ; ++j) {
    int par = PARENTS_d[j];
    if (lane < 16) {
      int r = lane >> 2, cc = lane & 3;
      float sacc = 0.f;
      #pragma unroll
      for (int k = 0; k < 4; ++k)
        sacc += A[par * 16 + r * 4 + k] * Tl[j * 16 + k * 4 + cc];
      A[j * 16 + lane] = sacc;
    }
    __syncthreads();
  }
  for (int idx = lane; idx < 165; idx += 64) {
    int j = idx / 3, r = idx % 3;
    out[JOFF + (size_t)b * 165 + idx] = A[j * 16 + r * 4 + 3];
  }
  for (int idx = lane; idx < 1024; idx += 64) {
    int n = idx >> 6, k = idx & 63;
    float val = 0.f;
    if (n < 12 && k < NJ) {
      int m = n >> 2, cc = n & 3;
      if (cc < 3) val = A[k * 16 + m * 4 + cc];
      else {
        val = A[k * 16 + m * 4 + 3]
            - (A[k * 16 + m * 4 + 0] * joints_l[k * 3 + 0] +
               A[k * 16 + m * 4 + 1] * joints_l[k * 3 + 1] +
               A[k * 16 + m * 4 + 2] * joints_l[k * 3 + 2]);
      }
    }
    arelb[(size_t)b * 1024 + idx] = f2b(val);
  }
}

// ---------------- K4: fused GEMM — packed-bf16 LDS staging ----------------
// out[b][r] = vt[r] + sum_k Ftr[b][k] * D[k][r];  D = [pd(486); sd cols(60); 0]
// LDS: pk[(k>>1)*PR + r_local] dword = (bf16(k even) | bf16(k odd)<<16)
__global__ __launch_bounds__(256) void k_gemm(
    const float* __restrict__ vt, const float* __restrict__ sd,
    const float* __restrict__ pd, const unsigned short* __restrict__ Ftr,
    float* __restrict__ out) {
  __shared__ unsigned int pk[2][16 * PR];
  int t = threadIdx.x;
  int lane = t & 63, wvv = t >> 6;
  int l15 = lane & 15, q = lane >> 4;
  int r0 = blockIdx.x * 64;
  int m0 = wvv * 64;
  int kp_ = t >> 4;            // k-pair 0..15
  int c4 = (t & 15) * 4;       // r offset group
  bool full = (r0 + 64 <= R3);

  float4_ acc[4][4];
  #pragma unroll
  for (int mt = 0; mt < 4; ++mt)
    #pragma unroll
    for (int nt = 0; nt < 4; ++nt) acc[mt][nt] = (float4_)0.f;

  const unsigned short* aBase[4];
  #pragma unroll
  for (int mt = 0; mt < 4; ++mt)
    aBase[mt] = Ftr + (size_t)(m0 + mt * 16 + l15) * KP + q * 8;

  // stage chunk 0 (all pd)
  {
    float v0[4], v1[4];
    int kg = kp_ * 2;
    #pragma unroll
    for (int i = 0; i < 4; ++i) {
      int r = r0 + c4 + i;
      bool ok = full || (r < R3);
      v0[i] = ok ? pd[(size_t)kg * R3 + r] : 0.f;
      v1[i] = ok ? pd[(size_t)(kg + 1) * R3 + r] : 0.f;
    }
    #pragma unroll
    for (int i = 0; i < 4; ++i)
      pk[0][kp_ * PR + c4 + i] =
          (unsigned)f2b(v0[i]) | ((unsigned)f2b(v1[i]) << 16);
  }
  __syncthreads();

  #pragma unroll 1
  for (int c = 0; c < 18; ++c) {
    int cur = c & 1;
    // ---- issue next chunk's global loads + convert ----
    unsigned int dnext[4];
    if (c < 17) {
      float v0[4], v1[4];
      int kg = (c + 1) * 32 + kp_ * 2;
      #pragma unroll
      for (int h = 0; h < 2; ++h) {
        int k = kg + h;
        float* dst = h ? v1 : v0;
        if (k < NP) {
          #pragma unroll
          for (int i = 0; i < 4; ++i) {
            int r = r0 + c4 + i;
            dst[i] = (full || r < R3) ? pd[(size_t)k * R3 + r] : 0.f;
          }
        } else if (k < NP + LB) {
          int ll = k - NP;
          int cidx = (ll < 10) ? ll : (290 + ll);
          #pragma unroll
          for (int i = 0; i < 4; ++i) {
            int r = r0 + c4 + i;
            dst[i] = (r < R3) ? sd[(size_t)r * 350 + cidx] : 0.f;
          }
        } else {
          #pragma unroll
          for (int i = 0; i < 4; ++i) dst[i] = 0.f;
        }
      }
      #pragma unroll
      for (int i = 0; i < 4; ++i)
        dnext[i] = (unsigned)f2b(v0[i]) | ((unsigned)f2b(v1[i]) << 16);
    }
    // ---- B frags from LDS: 4 dwords = 8 bf16 in k-order ----
    short8 bf[4];
    #pragma unroll
    for (int nt = 0; nt < 4; ++nt) {
      uint4_ u;
      #pragma unroll
      for (int jd = 0; jd < 4; ++jd)
        u[jd] = pk[cur][(q * 4 + jd) * PR + nt * 16 + l15];
      bf[nt] = __builtin_bit_cast(short8, u);
    }
    // ---- A frags (global, L2-resident) ----
    short8 af[4];
    #pragma unroll
    for (int mt = 0; mt < 4; ++mt)
      af[mt] = *(const short8*)(aBase[mt] + c * 32);
    // ---- MFMAs ----
    #pragma unroll
    for (int mt = 0; mt < 4; ++mt)
      #pragma unroll
      for (int nt = 0; nt < 4; ++nt)
        acc[mt][nt] = __builtin_amdgcn_mfma_f32_16x16x32_bf16(
            af[mt], bf[nt], acc[mt][nt], 0, 0, 0);
    // ---- write staged data to the other buffer ----
    if (c < 17) {
      #pragma unroll
      for (int i = 0; i < 4; ++i)
        pk[cur ^ 1][kp_ * PR + c4 + i] = dnext[i];
    }
    __syncthreads();
  }

  #pragma unroll
  for (int nt = 0; nt < 4; ++nt) {
    int r = r0 + nt * 16 + l15;
    if (r < R3) {
      float vtv = vt[r];
      #pragma unroll
      for (int mt = 0; mt < 4; ++mt) {
        int bb = m0 + mt * 16 + q * 4;
        #pragma unroll
        for (int reg = 0; reg < 4; ++reg)
          out[(size_t)(bb + reg) * R3 + r] = acc[mt][nt][reg] + vtv;
      }
    }
  }
}

// ---------------- K5: MFMA skinning, shfl-coalesced RMW -------------------
// MFMA: A=arelb (m=12 T-entries), B=W (n=16 v) => lane(q,l15): T[v][4q..4q+3]
// Apply: lane t<48 owns out element r = v0w*3 + t (coalesced); T via shfl.
__global__ __launch_bounds__(256) void k_skin(
    const unsigned short* __restrict__ Wb, const unsigned short* __restrict__ arelb,
    float* __restrict__ out) {
  int lane = threadIdx.x & 63;
  int wv = threadIdx.x >> 6;
  int l15 = lane & 15, q = lane >> 4;
  int v0w = blockIdx.x * 64 + wv * 16;
  int b0 = blockIdx.y * 16;

  const unsigned short* wp = Wb + (size_t)(v0w + l15) * 64 + q * 8;
  short8 w0 = *(const short8*)(wp);
  short8 w1 = *(const short8*)(wp + 32);

  int vi = lane / 3 >= 16 ? 15 : lane / 3;  // clamp for lanes 48..63
  vi = lane / 3;                            // (recomputed; lanes>=48 give vi>=16, unused)
  int ci = lane - vi * 3;
  int srcT = ci * 16 + (vi & 15);
  int srcX = (vi & 15) * 3 + ((vi >> 4) * 48);  // lanes>=48: src>=48 (garbage ok)
  srcX = vi * 3 <= 63 ? vi * 3 : 63;
  int r = v0w * 3 + lane;
  bool rok = (lane < 48) && (r < R3);

  float vload = 0.f;
  if (rok) vload = out[(size_t)b0 * R3 + r];
  const unsigned short* ap = arelb + (size_t)b0 * 1024 + l15 * 64 + q * 8;
  short8 a0 = *(const short8*)ap;
  short8 a1 = *(const short8*)(ap + 32);

  #pragma unroll 1
  for (int bi = 0; bi < 16; ++bi) {
    int b = b0 + bi;
    float nvload = 0.f;
    short8 na0 = a0, na1 = a1;
    if (bi < 15) {
      if (rok) nvload = out[(size_t)(b + 1) * R3 + r];
      const unsigned short* np = arelb + (size_t)(b + 1) * 1024 + l15 * 64 + q * 8;
      na0 = *(const short8*)np;
      na1 = *(const short8*)(np + 32);
    }
    float4_ acc = (float4_)0.f;
    acc = __builtin_amdgcn_mfma_f32_16x16x32_bf16(a0, w0, acc, 0, 0, 0);
    acc = __builtin_amdgcn_mfma_f32_16x16x32_bf16(a1, w1, acc, 0, 0, 0);
    float T0 = __shfl(acc[0], srcT, 64);
    float T1 = __shfl(acc[1], srcT, 64);
    float T2 = __shfl(acc[2], srcT, 64);
    float T3 = __shfl(acc[3], srcT, 64);
    float x = __shfl(vload, srcX, 64);
    float y = __shfl(vload, srcX + 1 <= 63 ? srcX + 1 : 63, 64);
    float z = __shfl(vload, srcX + 2 <= 63 ? srcX + 2 : 63, 64);
    if (rok) out[(size_t)b * R3 + r] = T0 * x + T1 * y + T2 * z + T3;
    vload = nvload; a0 = na0; a1 = na1;
  }
}

extern "C" void kernel_launch(void* const* d_in, const int* in_sizes, int n_in,
                              void* d_out, int out_size, void* d_ws, size_t ws_size,
                              hipStream_t stream) {
  const float* pose = (const float*)d_in[0];
  const float* shp  = (const float*)d_in[1];
  const float* expr = (const float*)d_in[2];
  const float* go   = (const float*)d_in[3];
  const float* vt   = (const float*)d_in[4];
  const float* sd   = (const float*)d_in[5];
  const float* pd   = (const float*)d_in[6];
  const float* jr   = (const float*)d_in[7];
  const float* lbs  = (const float*)d_in[8];
  float* out = (float*)d_out;
  float* ws  = (float*)d_ws;

  float* betas_T        = ws;                                 // 15360 fl
  float* rot_ws         = ws + 15360;                         // 126720 fl
  float* JS             = ws + 142080;                        // 10080 fl
  unsigned short* Ftr   = (unsigned short*)(ws + 152160);     // 73728 fl
  unsigned short* arelb = (unsigned short*)(ws + 225888);     // 131072 fl
  unsigned short* Wb    = (unsigned short*)(ws + 356960);     // VK*64 us = 335872 fl
  unsigned short* Jregb = (unsigned short*)(ws + 692832);     // 64*VK us = 335872 fl
  unsigned short* XbT   = (unsigned short*)(ws + 1028704);    // 192*VK us = 1007616 fl
  // total ~8.1 MB of d_ws

  hipMemsetAsync(JS, 0, 10080 * sizeof(float), stream);
  k_pose<<<NJ + 1, 256, 0, stream>>>(pose, shp, expr, go, rot_ws, Ftr, betas_T);
  k_jregb<<<(64 * VK) / 256, 256, 0, stream>>>(jr, Jregb);
  k_trX<<<VK / 64, 256, 0, stream>>>(sd, vt, XbT);
  k_jsm<<<VK / 64, 256, 0, stream>>>(Jregb, XbT, JS);
  k_wb<<<VK / 16, 256, 0, stream>>>(lbs, Wb);
  k_chain<<<BS, 64, 0, stream>>>(JS, betas_T, rot_ws, arelb, out);
  k_gemm<<<492, 256, 0, stream>>>(vt, sd, pd, Ftr, out);
  k_skin<<<dim3(164, 16), 256, 0, stream>>>(Wb, arelb, out);
}

// Round 7
// 296.391 us; speedup vs baseline: 1.1060x; 1.1060x over previous
//
#include <hip/hip_runtime.h>
#include <math.h>

#define BS 256
#define V 10475
#define NJ 55
#define R3 31425      // V*3
#define NP 486        // 54*9
#define LB 60         // effective betas (10 shape + 50 expression)
#define KP 576        // padded K (486 pose + 60 shape)
#define VK 10496      // V padded to mult of 128 (82*128)
#define JOFF 8044800  // BS*R3 — joints output offset
#define NKSPLIT 164   // jsm K-split blocks

// fused-pre block ranges
#define NB_POSE 56
#define NB_JREGB 2624   // 64*VK/256
#define NB_TRX 164      // VK/64
#define NB_WB 656       // VK/16
#define NB_TRD 4428     // 492*9
#define B0_JREGB (NB_POSE)
#define B0_TRX (B0_JREGB + NB_JREGB)
#define B0_WB (B0_TRX + NB_TRX)
#define B0_TRD (B0_WB + NB_WB)
#define NB_PRE (B0_TRD + NB_TRD)

typedef __attribute__((ext_vector_type(8))) short short8;
typedef __attribute__((ext_vector_type(4))) float float4_;

__device__ const int PARENTS_d[NJ] = {
  -1, 0, 0, 0, 1, 2, 3, 4, 5, 6, 7, 8, 9, 9, 9, 12, 13, 14, 16, 17, 18, 19,
  15, 15, 15, 20, 25, 26, 20, 28, 29, 20, 31, 32, 20, 34, 35, 20, 37, 38,
  21, 40, 41, 21, 43, 44, 21, 46, 47, 21, 49, 50, 21, 52, 53
};

__device__ __forceinline__ unsigned short f2b(float f) {
  unsigned int u = __float_as_uint(f);
  unsigned int r = (u + 0x7FFFu + ((u >> 16) & 1u)) >> 16;
  return (unsigned short)r;
}

// ============ K1 (fused prep): pose | jregb | trX | wb | trD ==============
__global__ __launch_bounds__(256) void k_pre(
    const float* __restrict__ pose, const float* __restrict__ shp,
    const float* __restrict__ expr, const float* __restrict__ go,
    const float* __restrict__ Jreg, const float* __restrict__ lbs,
    const float* __restrict__ sd, const float* __restrict__ vt,
    const float* __restrict__ pd,
    float* __restrict__ rot_ws, unsigned short* __restrict__ Ftr,
    float* __restrict__ betas_T, unsigned short* __restrict__ Jregb,
    unsigned short* __restrict__ Wb, unsigned short* __restrict__ XbT,
    unsigned short* __restrict__ Dtr) {
  __shared__ float smem[64 * 68];
  int blk = blockIdx.x;
  int t = threadIdx.x;

  if (blk < NB_POSE) {
    // ---------------- pose / betas ----------------
    int b = t;
    int j = blk;
    if (j == NJ) {
      #pragma unroll
      for (int l = 0; l < 10; ++l) {
        float v = shp[b * 10 + l];
        betas_T[l * BS + b] = v;
        Ftr[(size_t)b * KP + NP + l] = f2b(v);
      }
      #pragma unroll
      for (int l = 0; l < 50; ++l) {
        float v = expr[b * 50 + l];
        betas_T[(10 + l) * BS + b] = v;
        Ftr[(size_t)b * KP + NP + 10 + l] = f2b(v);
      }
      #pragma unroll
      for (int l = NP + LB; l < KP; ++l) Ftr[(size_t)b * KP + l] = 0;
      return;
    }
    float rx, ry, rz;
    if (j == 0) { rx = go[0]; ry = go[1]; rz = go[2]; }
    else if (j == 23 || j == 24) { rx = 0.f; ry = 0.f; rz = 0.f; }
    else {
      int src = (j <= 21) ? j : (j == 22 ? 52 : j - 3);
      const float* p = pose + ((size_t)b * 53 + src) * 3;
      rx = p[0]; ry = p[1]; rz = p[2];
    }
    float sx = rx + 1e-8f, sy = ry + 1e-8f, sz = rz + 1e-8f;
    float ang = sqrtf(sx * sx + sy * sy + sz * sz);
    float inv = 1.f / ang;
    float x = rx * inv, y = ry * inv, z = rz * inv;
    float s = sinf(ang), c = cosf(ang), C = 1.f - c;
    float R[9];
    R[0] = 1.f - C * (y * y + z * z);
    R[1] = -s * z + C * x * y;
    R[2] =  s * y + C * x * z;
    R[3] =  s * z + C * x * y;
    R[4] = 1.f - C * (x * x + z * z);
    R[5] = -s * x + C * y * z;
    R[6] = -s * y + C * x * z;
    R[7] =  s * x + C * y * z;
    R[8] = 1.f - C * (x * x + y * y);
    float* rw = rot_ws + ((size_t)b * NJ + j) * 9;
    #pragma unroll
    for (int e = 0; e < 9; ++e) rw[e] = R[e];
    if (j >= 1) {
      int pb = (j - 1) * 9;
      #pragma unroll
      for (int e = 0; e < 9; ++e)
        Ftr[(size_t)b * KP + pb + e] =
            f2b(R[e] - ((e == 0 || e == 4 || e == 8) ? 1.f : 0.f));
    }
  } else if (blk < B0_TRX) {
    // ---------------- Jregb: bf16 pad(Jreg) [64][VK] ----------------
    size_t idx = (size_t)(blk - B0_JREGB) * 256 + t;
    int j = (int)(idx / VK);
    int v = (int)(idx - (size_t)j * VK);
    float val = (j < NJ && v < V) ? Jreg[(size_t)j * V + v] : 0.f;
    Jregb[idx] = f2b(val);
  } else if (blk < B0_WB) {
    // ---------------- trX: XbT[192][VK] bf16, per-c phases ----------------
    int v0 = (blk - B0_TRX) * 64;
    #pragma unroll 1
    for (int c = 0; c < 3; ++c) {
      for (int idx = t; idx < 3840; idx += 256) {
        int v_l = idx / 60, col = idx - v_l * 60;
        int v = v0 + v_l;
        int cidx = (col < 10) ? col : 290 + col;
        smem[col * 65 + v_l] = (v < V) ? sd[((size_t)v * 3 + c) * 350 + cidx] : 0.f;
      }
      {
        int v_l = t & 63, rr = t >> 6;  // rr 0..3 -> rows 60..63
        int v = v0 + v_l;
        smem[(60 + rr) * 65 + v_l] =
            (rr == 0 && v < V) ? vt[(size_t)v * 3 + c] : 0.f;
      }
      __syncthreads();
      for (int idx = t; idx < 4096; idx += 256) {
        int cl = idx >> 6, v_l = idx & 63;
        XbT[(size_t)(c * 64 + cl) * VK + v0 + v_l] = f2b(smem[cl * 65 + v_l]);
      }
      __syncthreads();
    }
  } else if (blk < B0_TRD) {
    // ---------------- Wb[v][64] bf16 ----------------
    int v0 = (blk - B0_WB) * 16;
    for (int idx = t; idx < 1024; idx += 256) {
      int v_l = idx >> 6, k = idx & 63;
      int v = v0 + v_l;
      float val = (k < NJ && v < V) ? lbs[(size_t)v * NJ + k] : 0.f;
      if (v < VK) Wb[(size_t)v * 64 + k] = f2b(val);
    }
  } else {
    // ---------------- trD: Dtr[r][KP] bf16 = transpose([pd; sd cols]) -----
    int b2 = blk - B0_TRD;
    int rt = b2 % 492, kt = b2 / 492;
    int r0 = rt * 64;
    int c = (t & 15) * 4;
    #pragma unroll
    for (int s = 0; s < 4; ++s) {
      int k_l = (t >> 4) + 16 * s;
      int kg = kt * 64 + k_l;
      float v0 = 0.f, v1 = 0.f, v2 = 0.f, v3 = 0.f;
      int r = r0 + c;
      if (kg < NP) {
        if (r + 3 < R3) {
          const float* p = pd + (size_t)kg * R3 + r;
          v0 = p[0]; v1 = p[1]; v2 = p[2]; v3 = p[3];
        } else {
          const float* p = pd + (size_t)kg * R3;
          if (r < R3)     v0 = p[r];
          if (r + 1 < R3) v1 = p[r + 1];
          if (r + 2 < R3) v2 = p[r + 2];
          if (r + 3 < R3) v3 = p[r + 3];
        }
      } else if (kg < NP + LB) {
        int ll = kg - NP;
        int cidx = (ll < 10) ? ll : (290 + ll);
        if (r < R3)     v0 = sd[(size_t)(r) * 350 + cidx];
        if (r + 1 < R3) v1 = sd[(size_t)(r + 1) * 350 + cidx];
        if (r + 2 < R3) v2 = sd[(size_t)(r + 2) * 350 + cidx];
        if (r + 3 < R3) v3 = sd[(size_t)(r + 3) * 350 + cidx];
      }
      float* tp = smem + k_l * 68 + c;
      tp[0] = v0; tp[1] = v1; tp[2] = v2; tp[3] = v3;
    }
    __syncthreads();
    int r_l = t >> 2, a = t & 3;
    unsigned short h[16];
    #pragma unroll
    for (int i = 0; i < 16; ++i) h[i] = f2b(smem[(a * 16 + i) * 68 + r_l]);
    unsigned short* dp = Dtr + (size_t)(r0 + r_l) * KP + kt * 64 + a * 16;
    #pragma unroll
    for (int i = 0; i < 16; ++i) dp[i] = h[i];
  }
}

// ============ K2: JS partials via MFMA — M=64(j) N=192 K=64/block =========
__global__ __launch_bounds__(256) void k_jsm(
    const unsigned short* __restrict__ Jregb,
    const unsigned short* __restrict__ XbT, float* __restrict__ Ppart) {
  int lane = threadIdx.x & 63;
  int wv = threadIdx.x >> 6;
  int l15 = lane & 15, q = lane >> 4;
  int k0 = blockIdx.x * 64;
  const unsigned short* ap = Jregb + (size_t)(wv * 16 + l15) * VK + k0 + q * 8;
  float4_ acc[12];
  #pragma unroll
  for (int nt = 0; nt < 12; ++nt) acc[nt] = (float4_)0.f;
  #pragma unroll
  for (int ks = 0; ks < 2; ++ks) {
    short8 a = *(const short8*)(ap + ks * 32);
    #pragma unroll
    for (int nt = 0; nt < 12; ++nt) {
      const unsigned short* bp =
          XbT + (size_t)(nt * 16 + l15) * VK + k0 + ks * 32 + q * 8;
      short8 b = *(const short8*)bp;
      acc[nt] = __builtin_amdgcn_mfma_f32_16x16x32_bf16(a, b, acc[nt], 0, 0, 0);
    }
  }
  float* pp = Ppart + (size_t)blockIdx.x * 10080;
  #pragma unroll
  for (int nt = 0; nt < 12; ++nt) {
    int cl = nt * 16 + l15;
    int c = cl >> 6, l = cl & 63;
    if (l < 61) {
      #pragma unroll
      for (int reg = 0; reg < 4; ++reg) {
        int jj = wv * 16 + q * 4 + reg;
        if (jj < NJ) pp[((size_t)jj * 3 + c) * 61 + l] = acc[nt][reg];
      }
    }
  }
}

// ============ K2b: JS = sum of partials ===================================
__global__ __launch_bounds__(256) void k_jsred(
    const float* __restrict__ Ppart, float* __restrict__ JS) {
  int idx = blockIdx.x * 256 + threadIdx.x;
  if (idx >= 10065) return;
  float s = 0.f;
  #pragma unroll 4
  for (int p = 0; p < NKSPLIT; ++p) s += Ppart[(size_t)p * 10080 + idx];
  JS[idx] = s;
}

// ============ K3: joints + kinematic chain + arelb bf16 ===================
__global__ __launch_bounds__(64) void k_chain(
    const float* __restrict__ JS, const float* __restrict__ betas_T,
    const float* __restrict__ rot_ws, unsigned short* __restrict__ arelb,
    float* __restrict__ out) {
  int b = blockIdx.x;
  int lane = threadIdx.x;
  __shared__ float joints_l[165];
  __shared__ float Tl[880];
  __shared__ float A[880];
  for (int idx = lane; idx < 165; idx += 64) {
    float sacc = JS[idx * 61 + 60];  // v_template column
    #pragma unroll
    for (int l = 0; l < LB; ++l) sacc += JS[idx * 61 + l] * betas_T[l * BS + b];
    joints_l[idx] = sacc;
  }
  __syncthreads();
  for (int idx = lane; idx < 880; idx += 64) {
    int j = idx >> 4, e = idx & 15, r = e >> 2, cc = e & 3;
    float val;
    if (r < 3) {
      if (cc < 3) val = rot_ws[((size_t)b * NJ + j) * 9 + r * 3 + cc];
      else {
        int par = PARENTS_d[j];
        val = joints_l[j * 3 + r] - (par >= 0 ? joints_l[par * 3 + r] : 0.f);
      }
    } else val = (cc == 3) ? 1.f : 0.f;
    Tl[idx] = val;
  }
  __syncthreads();
  if (lane < 16) A[lane] = Tl[lane];
  __syncthreads();
  for (int j = 1; j < NJ; ++j) {
    int par = PARENTS_d[j];
    if (lane < 16) {
      int r = lane >> 2, cc = lane & 3;
      float sacc = 0.f;
      #pragma unroll
      for (int k = 0; k < 4; ++k)
        sacc += A[par * 16 + r * 4 + k] * Tl[j * 16 + k * 4 + cc];
      A[j * 16 + lane] = sacc;
    }
    __syncthreads();
  }
  for (int idx = lane; idx < 165; idx += 64) {
    int j = idx / 3, r = idx % 3;
    out[JOFF + (size_t)b * 165 + idx] = A[j * 16 + r * 4 + 3];
  }
  for (int idx = lane; idx < 1024; idx += 64) {
    int n = idx >> 6, k = idx & 63;
    float val = 0.f;
    if (n < 12 && k < NJ) {
      int m = n >> 2, cc = n & 3;
      if (cc < 3) val = A[k * 16 + m * 4 + cc];
      else {
        val = A[k * 16 + m * 4 + 3]
            - (A[k * 16 + m * 4 + 0] * joints_l[k * 3 + 0] +
               A[k * 16 + m * 4 + 1] * joints_l[k * 3 + 1] +
               A[k * 16 + m * 4 + 2] * joints_l[k * 3 + 2]);
      }
    }
    arelb[(size_t)b * 1024 + idx] = f2b(val);
  }
}

// ============ K4: register MFMA GEMM  out[b][r] = vt[r] + Ftr·Dtr^T =======
// block: 64 r x 256 b; wave: 64 b (4 m-tiles) x 64 r (4 n-tiles); no LDS
__global__ __launch_bounds__(256) void k_gemm(
    const float* __restrict__ vt, const unsigned short* __restrict__ Ftr,
    const unsigned short* __restrict__ Dtr, float* __restrict__ out) {
  int lane = threadIdx.x & 63;
  int wv = threadIdx.x >> 6;
  int l15 = lane & 15, q = lane >> 4;
  int r0 = blockIdx.x * 64;
  int m0 = wv * 64;
  float4_ acc[4][4];
  #pragma unroll
  for (int mt = 0; mt < 4; ++mt)
    #pragma unroll
    for (int nt = 0; nt < 4; ++nt) acc[mt][nt] = (float4_)0.f;

  const unsigned short* aBase[4];
  const unsigned short* bBase[4];
  #pragma unroll
  for (int mt = 0; mt < 4; ++mt)
    aBase[mt] = Ftr + (size_t)(m0 + mt * 16 + l15) * KP + q * 8;
  #pragma unroll
  for (int nt = 0; nt < 4; ++nt)
    bBase[nt] = Dtr + (size_t)(r0 + nt * 16 + l15) * KP + q * 8;

  short8 af[4], bf[4], an[4], bn[4];
  #pragma unroll
  for (int mt = 0; mt < 4; ++mt) af[mt] = *(const short8*)(aBase[mt]);
  #pragma unroll
  for (int nt = 0; nt < 4; ++nt) bf[nt] = *(const short8*)(bBase[nt]);

  #pragma unroll 1
  for (int kk = 0; kk < 18; ++kk) {
    if (kk < 17) {
      int off = (kk + 1) * 32;
      #pragma unroll
      for (int mt = 0; mt < 4; ++mt) an[mt] = *(const short8*)(aBase[mt] + off);
      #pragma unroll
      for (int nt = 0; nt < 4; ++nt) bn[nt] = *(const short8*)(bBase[nt] + off);
    }
    #pragma unroll
    for (int mt = 0; mt < 4; ++mt)
      #pragma unroll
      for (int nt = 0; nt < 4; ++nt)
        acc[mt][nt] = __builtin_amdgcn_mfma_f32_16x16x32_bf16(
            af[mt], bf[nt], acc[mt][nt], 0, 0, 0);
    #pragma unroll
    for (int mt = 0; mt < 4; ++mt) af[mt] = an[mt];
    #pragma unroll
    for (int nt = 0; nt < 4; ++nt) bf[nt] = bn[nt];
  }

  #pragma unroll
  for (int nt = 0; nt < 4; ++nt) {
    int r = r0 + nt * 16 + l15;
    if (r < R3) {
      float vtv = vt[r];
      #pragma unroll
      for (int mt = 0; mt < 4; ++mt) {
        int bb = m0 + mt * 16 + q * 4;
        #pragma unroll
        for (int reg = 0; reg < 4; ++reg)
          out[(size_t)(bb + reg) * R3 + r] = acc[mt][nt][reg] + vtv;
      }
    }
  }
}

// ============ K5: MFMA skinning, shfl-coalesced RMW =======================
__global__ __launch_bounds__(256) void k_skin(
    const unsigned short* __restrict__ Wb, const unsigned short* __restrict__ arelb,
    float* __restrict__ out) {
  int lane = threadIdx.x & 63;
  int wv = threadIdx.x >> 6;
  int l15 = lane & 15, q = lane >> 4;
  int v0w = blockIdx.x * 64 + wv * 16;
  int b0 = blockIdx.y * 16;

  const unsigned short* wp = Wb + (size_t)(v0w + l15) * 64 + q * 8;
  short8 w0 = *(const short8*)(wp);
  short8 w1 = *(const short8*)(wp + 32);

  int vi = lane / 3;
  int ci = lane - vi * 3;
  int srcT = ci * 16 + (vi & 15);
  int srcX = vi * 3 <= 63 ? vi * 3 : 63;
  int r = v0w * 3 + lane;
  bool rok = (lane < 48) && (r < R3);

  float vload = 0.f;
  if (rok) vload = out[(size_t)b0 * R3 + r];
  const unsigned short* ap = arelb + (size_t)b0 * 1024 + l15 * 64 + q * 8;
  short8 a0 = *(const short8*)ap;
  short8 a1 = *(const short8*)(ap + 32);

  #pragma unroll 1
  for (int bi = 0; bi < 16; ++bi) {
    int b = b0 + bi;
    float nvload = 0.f;
    short8 na0 = a0, na1 = a1;
    if (bi < 15) {
      if (rok) nvload = out[(size_t)(b + 1) * R3 + r];
      const unsigned short* np = arelb + (size_t)(b + 1) * 1024 + l15 * 64 + q * 8;
      na0 = *(const short8*)np;
      na1 = *(const short8*)(np + 32);
    }
    float4_ acc = (float4_)0.f;
    acc = __builtin_amdgcn_mfma_f32_16x16x32_bf16(a0, w0, acc, 0, 0, 0);
    acc = __builtin_amdgcn_mfma_f32_16x16x32_bf16(a1, w1, acc, 0, 0, 0);
    float T0 = __shfl(acc[0], srcT, 64);
    float T1 = __shfl(acc[1], srcT, 64);
    float T2 = __shfl(acc[2], srcT, 64);
    float T3 = __shfl(acc[3], srcT, 64);
    float x = __shfl(vload, srcX, 64);
    float y = __shfl(vload, srcX + 1 <= 63 ? srcX + 1 : 63, 64);
    float z = __shfl(vload, srcX + 2 <= 63 ? srcX + 2 : 63, 64);
    if (rok) out[(size_t)b * R3 + r] = T0 * x + T1 * y + T2 * z + T3;
    vload = nvload; a0 = na0; a1 = na1;
  }
}

extern "C" void kernel_launch(void* const* d_in, const int* in_sizes, int n_in,
                              void* d_out, int out_size, void* d_ws, size_t ws_size,
                              hipStream_t stream) {
  const float* pose = (const float*)d_in[0];
  const float* shp  = (const float*)d_in[1];
  const float* expr = (const float*)d_in[2];
  const float* go   = (const float*)d_in[3];
  const float* vt   = (const float*)d_in[4];
  const float* sd   = (const float*)d_in[5];
  const float* pd   = (const float*)d_in[6];
  const float* jr   = (const float*)d_in[7];
  const float* lbs  = (const float*)d_in[8];
  float* out = (float*)d_out;
  float* ws  = (float*)d_ws;

  float* betas_T        = ws;                                 // 15360 fl
  float* rot_ws         = ws + 15360;                         // 126720 fl
  float* JS             = ws + 142080;                        // 10080 fl
  unsigned short* Ftr   = (unsigned short*)(ws + 152160);     // 73728 fl
  unsigned short* arelb = (unsigned short*)(ws + 225888);     // 131072 fl
  unsigned short* Wb    = (unsigned short*)(ws + 356960);     // 335872 fl
  unsigned short* Jregb = (unsigned short*)(ws + 692832);     // 335872 fl
  unsigned short* XbT   = (unsigned short*)(ws + 1028704);    // 1007616 fl
  unsigned short* Dtr   = (unsigned short*)(ws + 2036320);    // 31488*576 us = 9068544 fl
  float* Ppart          = ws + 11104864;                      // 164*10080 = 1653120 fl
  // total ~51 MB of d_ws

  k_pre<<<NB_PRE, 256, 0, stream>>>(pose, shp, expr, go, jr, lbs, sd, vt, pd,
                                    rot_ws, Ftr, betas_T, Jregb, Wb, XbT, Dtr);
  k_jsm<<<NKSPLIT, 256, 0, stream>>>(Jregb, XbT, Ppart);
  k_jsred<<<40, 256, 0, stream>>>(Ppart, JS);
  k_chain<<<BS, 64, 0, stream>>>(JS, betas_T, rot_ws, arelb, out);
  k_gemm<<<492, 256, 0, stream>>>(vt, Ftr, Dtr, out);
  k_skin<<<dim3(164, 16), 256, 0, stream>>>(Wb, arelb, out);
}